// Round 13
// baseline (310.925 us; speedup 1.0000x reference)
//
#include <hip/hip_runtime.h>
#include <hip/hip_bf16.h>
#include <math.h>

// Problem constants
#define BATCH 4
#define LSEQ  1024
#define DIM   256
#define ESZ   512      // E = 2*DIM
#define NST   32       // D_STATE
#define RNK   16       // DT_RANK
#define MROWS 4096     // B*L
#define NCH   64       // scan chunks
#define CHL   16       // chunk length

typedef __attribute__((ext_vector_type(8))) short bf16x8;
typedef __attribute__((ext_vector_type(4))) float f32x4;

__device__ __forceinline__ float silu_f(float v) { return v / (1.f + __expf(-v)); }
__device__ __forceinline__ float softplus_f(float v) {
    return (v > 20.f) ? v : log1pf(__expf(v));
}

// ---------------------------------------------------------------------------
// prep: [blocks 0..935] weight fp32->bf16 conversions
//       [blocks 936..5031] fused LN1 + dwconv3 + residual -> bf16 hm
// ---------------------------------------------------------------------------
__global__ __launch_bounds__(256) void prep_kernel(
    const float* __restrict__ ipw, const float* __restrict__ opw,
    const float* __restrict__ w1,  const float* __restrict__ w2,
    const float* __restrict__ xpw, __hip_bfloat16* __restrict__ dst,
    const float* __restrict__ x, const float* __restrict__ g,
    const float* __restrict__ b, const float* __restrict__ cw,
    const float* __restrict__ cb, __hip_bfloat16* __restrict__ hm)
{
    if (blockIdx.x < 936) {
        int i = blockIdx.x * 256 + threadIdx.x;   // over 239616 float4s
        if (i >= 239616) return;
        const float* s; int off;
        if      (i < 65536)  { s = ipw; off = i; }
        else if (i < 98304)  { s = opw; off = i - 65536; }
        else if (i < 163840) { s = w1;  off = i - 98304; }
        else if (i < 229376) { s = w2;  off = i - 163840; }
        else                 { s = xpw; off = i - 229376; }
        float4 v = ((const float4*)s)[off];
        union { __hip_bfloat16 h[4]; short4 s4; } u;
        u.h[0] = __float2bfloat16(v.x);
        u.h[1] = __float2bfloat16(v.y);
        u.h[2] = __float2bfloat16(v.z);
        u.h[3] = __float2bfloat16(v.w);
        ((short4*)dst)[i] = u.s4;
        return;
    }
    const int row = blockIdx.x - 936;
    const int l   = row & (LSEQ - 1);
    const int d   = threadIdx.x;
    const float gc = g[d], bc = b[d];

    float xc = x[row * DIM + d];
    float xl = (l > 0)        ? x[(row - 1) * DIM + d] : 0.f;
    float xr = (l < LSEQ - 1) ? x[(row + 1) * DIM + d] : 0.f;

    float a[6] = { xc, xc * xc, xl, xl * xl, xr, xr * xr };
    #pragma unroll
    for (int o = 32; o > 0; o >>= 1)
        #pragma unroll
        for (int j = 0; j < 6; ++j) a[j] += __shfl_down(a[j], o, 64);
    __shared__ float red[4][6];
    if ((d & 63) == 0)
        #pragma unroll
        for (int j = 0; j < 6; ++j) red[d >> 6][j] = a[j];
    __syncthreads();
    float t[6];
    #pragma unroll
    for (int j = 0; j < 6; ++j)
        t[j] = red[0][j] + red[1][j] + red[2][j] + red[3][j];

    auto ln = [&](float v, float s, float s2) {
        float m  = s * (1.f / DIM);
        float vr = s2 * (1.f / DIM) - m * m;
        return (v - m) * rsqrtf(vr + 1e-5f) * gc + bc;
    };
    float ln_c = ln(xc, t[0], t[1]);
    float acc  = cw[d * 3 + 1] * ln_c + cb[d] + ln_c;
    if (l > 0)        acc += cw[d * 3 + 0] * ln(xl, t[2], t[3]);
    if (l < LSEQ - 1) acc += cw[d * 3 + 2] * ln(xr, t[4], t[5]);
    hm[row * DIM + d] = __float2bfloat16(acc);
}

// ---------------------------------------------------------------------------
// Plain LayerNorm (LN2) -> bf16
// ---------------------------------------------------------------------------
__global__ __launch_bounds__(256) void ln_kernel(
    const float* __restrict__ x, const float* __restrict__ g,
    const float* __restrict__ b, __hip_bfloat16* __restrict__ y)
{
    const int row = blockIdx.x;
    const int tid = threadIdx.x;
    float v = x[row * DIM + tid];
    float s = v, s2 = v * v;
    #pragma unroll
    for (int o = 32; o > 0; o >>= 1) {
        s  += __shfl_down(s,  o, 64);
        s2 += __shfl_down(s2, o, 64);
    }
    __shared__ float ls[4], ls2[4];
    if ((tid & 63) == 0) { ls[tid >> 6] = s; ls2[tid >> 6] = s2; }
    __syncthreads();
    float ts  = ls[0]  + ls[1]  + ls[2]  + ls[3];
    float ts2 = ls2[0] + ls2[1] + ls2[2] + ls2[3];
    float mean = ts * (1.f / DIM);
    float var  = ts2 * (1.f / DIM) - mean * mean;
    float inv  = rsqrtf(var + 1e-5f);
    y[row * DIM + tid] =
        __float2bfloat16((v - mean) * inv * g[tid] + b[tid]);
}

// ---------------------------------------------------------------------------
// causal dwconv4 + SiLU -> bf16 ub (for x_proj). Reads bf16 xz.
// ---------------------------------------------------------------------------
__global__ __launch_bounds__(256) void conv4_silu_kernel(
    const __hip_bfloat16* __restrict__ xz, const float* __restrict__ w,
    const float* __restrict__ cb, __hip_bfloat16* __restrict__ ub)
{
    const int i  = blockIdx.x * 256 + threadIdx.x;   // over 4096*512
    const int e  = i & (ESZ - 1);
    const int bl = i >> 9;
    const int l  = bl & (LSEQ - 1);
    float acc = cb[e];
    #pragma unroll
    for (int k = 0; k < 4; ++k) {
        int ls = l + k - 3;
        if (ls >= 0)
            acc += w[e * 4 + k] * __bfloat162float(xz[(long)(bl + k - 3) * 1024 + e]);
    }
    ub[(long)bl * ESZ + e] = __float2bfloat16(silu_f(acc));
}

// ---------------------------------------------------------------------------
// Epilogue ids
// ---------------------------------------------------------------------------
#define EPI_NONE      0
#define EPI_GELU      2
#define EPI_RES       3
#define EPI_BIAS_RES  4

// ---------------------------------------------------------------------------
// bf16 MFMA GEMM with reg prefetch. C = A @ W^T (+ epilogue). BM=64.
// ---------------------------------------------------------------------------
template <int BM, int BN, int EPI, int OUT_BF16>
__global__ __launch_bounds__(256) void gemm_mfma(
    const __hip_bfloat16* __restrict__ A, int lda,
    const __hip_bfloat16* __restrict__ W, int ldw,
    void* __restrict__ Cout, int ldc, int K,
    const float* __restrict__ bias,
    const float* __restrict__ res, int ldres)
{
    constexpr int BK = 64;
    constexpr int LS = BK + 8;
    constexpr int WAVES_N = 4;
    constexpr int WTN = BN / WAVES_N;
    constexpr int AMF = 4;
    constexpr int BNF = WTN / 16;
    constexpr int AR = BM / 32;
    constexpr int BR = BN / 32;

    __shared__ __hip_bfloat16 As[BM * LS];
    __shared__ __hip_bfloat16 Ws[BN * LS];

    const int tid  = threadIdx.x;
    const int lane = tid & 63;
    const int wave = tid >> 6;
    const int wn   = wave * WTN;
    const int m0   = blockIdx.x * BM;
    const int n0   = blockIdx.y * BN;
    const int srow = tid >> 3;
    const int scol = (tid & 7) * 8;
    const int q    = lane >> 4;
    const int lr   = lane & 15;

    f32x4 acc[AMF][BNF];
    #pragma unroll
    for (int i = 0; i < AMF; ++i)
        #pragma unroll
        for (int j = 0; j < BNF; ++j)
            acc[i][j] = (f32x4){0.f, 0.f, 0.f, 0.f};

    const __hip_bfloat16* Ab = A + (long)m0 * lda;
    const __hip_bfloat16* Wb = W + (long)n0 * ldw;

    float4 ar[AR], wr[BR];
    #pragma unroll
    for (int r = 0; r < AR; ++r)
        ar[r] = *(const float4*)(Ab + (long)(r * 32 + srow) * lda + scol);
    #pragma unroll
    for (int r = 0; r < BR; ++r)
        wr[r] = *(const float4*)(Wb + (long)(r * 32 + srow) * ldw + scol);

    for (int k0 = 0; k0 < K; k0 += BK) {
        __syncthreads();
        #pragma unroll
        for (int r = 0; r < AR; ++r)
            *(float4*)(&As[(r * 32 + srow) * LS + scol]) = ar[r];
        #pragma unroll
        for (int r = 0; r < BR; ++r)
            *(float4*)(&Ws[(r * 32 + srow) * LS + scol]) = wr[r];
        __syncthreads();
        if (k0 + BK < K) {
            #pragma unroll
            for (int r = 0; r < AR; ++r)
                ar[r] = *(const float4*)(Ab + (long)(r * 32 + srow) * lda + k0 + BK + scol);
            #pragma unroll
            for (int r = 0; r < BR; ++r)
                wr[r] = *(const float4*)(Wb + (long)(r * 32 + srow) * ldw + k0 + BK + scol);
        }
        #pragma unroll
        for (int ks = 0; ks < 2; ++ks) {
            bf16x8 af[AMF], bfr[BNF];
            #pragma unroll
            for (int i = 0; i < AMF; ++i)
                af[i] = *(const bf16x8*)(&As[(i * 16 + lr) * LS + ks * 32 + q * 8]);
            #pragma unroll
            for (int j = 0; j < BNF; ++j)
                bfr[j] = *(const bf16x8*)(&Ws[(wn + j * 16 + lr) * LS + ks * 32 + q * 8]);
            #pragma unroll
            for (int i = 0; i < AMF; ++i)
                #pragma unroll
                for (int j = 0; j < BNF; ++j)
                    acc[i][j] = __builtin_amdgcn_mfma_f32_16x16x32_bf16(
                        af[i], bfr[j], acc[i][j], 0, 0, 0);
        }
    }

    #pragma unroll
    for (int i = 0; i < AMF; ++i) {
        #pragma unroll
        for (int j = 0; j < BNF; ++j) {
            const int col  = n0 + wn + j * 16 + lr;
            const int rowb = m0 + i * 16 + q * 4;
            #pragma unroll
            for (int r = 0; r < 4; ++r) {
                const int row = rowb + r;
                float v = acc[i][j][r];
                if (EPI == EPI_GELU) {
                    v += bias[col];
                    v = 0.5f * v * (1.f + erff(v * 0.70710678118654752f));
                } else if (EPI == EPI_RES) {
                    v += res[(long)row * ldres + col];
                } else if (EPI == EPI_BIAS_RES) {
                    v += bias[col] + res[(long)row * ldres + col];
                }
                if (OUT_BF16)
                    ((__hip_bfloat16*)Cout)[(long)row * ldc + col] = __float2bfloat16(v);
                else
                    ((float*)Cout)[(long)row * ldc + col] = v;
            }
        }
    }
}

// ---------------------------------------------------------------------------
// x_proj MFMA + dt epilogue: dbl[4096,80] = ub[4096,512] @ xpwb[80,512]^T,
// reg prefetch; then dtf[row,e] = softplus(dtb[e] + dbl[row,:16].dtw[e,:])
// computed from the block's rank-column accumulators via LDS (no dt_kernel,
// no dbl re-read). NOTE: the R7 regression was the fused *staging*, not the
// tail — staging here is the proven plain ub load.
// ---------------------------------------------------------------------------
__global__ __launch_bounds__(256) void xproj_mfma_dt(
    const __hip_bfloat16* __restrict__ A,
    const __hip_bfloat16* __restrict__ W,
    const float* __restrict__ dtw, const float* __restrict__ dtb,
    float* __restrict__ C, __hip_bfloat16* __restrict__ dtf)
{
    constexpr int LS = 72;
    __shared__ __hip_bfloat16 As[64 * LS];
    __shared__ __hip_bfloat16 Ws[80 * LS];
    __shared__ float sRank[64][17];
    const int tid  = threadIdx.x;
    const int lane = tid & 63;
    const int wave = tid >> 6;
    const int wm   = wave * 16;
    const int m0   = blockIdx.x * 64;
    const int srow = tid >> 3;
    const int scol = (tid & 7) * 8;
    const int q    = lane >> 4;
    const int lr   = lane & 15;

    f32x4 acc[5];
    #pragma unroll
    for (int j = 0; j < 5; ++j) acc[j] = (f32x4){0.f, 0.f, 0.f, 0.f};

    float4 ar[2], wr[3];
    #pragma unroll
    for (int r = 0; r < 2; ++r)
        ar[r] = *(const float4*)(A + (long)(m0 + r * 32 + srow) * 512 + scol);
    #pragma unroll
    for (int r = 0; r < 3; ++r) {
        int row = r * 32 + srow;
        wr[r] = (row < 80) ? *(const float4*)(W + (long)row * 512 + scol)
                           : make_float4(0.f, 0.f, 0.f, 0.f);
    }

    for (int k0 = 0; k0 < 512; k0 += 64) {
        __syncthreads();
        #pragma unroll
        for (int r = 0; r < 2; ++r)
            *(float4*)(&As[(r * 32 + srow) * LS + scol]) = ar[r];
        #pragma unroll
        for (int r = 0; r < 3; ++r) {
            int row = r * 32 + srow;
            if (row < 80) *(float4*)(&Ws[row * LS + scol]) = wr[r];
        }
        __syncthreads();
        if (k0 + 64 < 512) {
            #pragma unroll
            for (int r = 0; r < 2; ++r)
                ar[r] = *(const float4*)(A + (long)(m0 + r * 32 + srow) * 512 + k0 + 64 + scol);
            #pragma unroll
            for (int r = 0; r < 3; ++r) {
                int row = r * 32 + srow;
                if (row < 80)
                    wr[r] = *(const float4*)(W + (long)row * 512 + k0 + 64 + scol);
            }
        }
        #pragma unroll
        for (int ks = 0; ks < 2; ++ks) {
            bf16x8 af = *(const bf16x8*)(&As[(wm + lr) * LS + ks * 32 + q * 8]);
            #pragma unroll
            for (int j = 0; j < 5; ++j) {
                bf16x8 bf = *(const bf16x8*)(&Ws[(j * 16 + lr) * LS + ks * 32 + q * 8]);
                acc[j] = __builtin_amdgcn_mfma_f32_16x16x32_bf16(af, bf, acc[j], 0, 0, 0);
            }
        }
    }
    // write dbl; stage rank cols (frag j=0 -> cols 0..15) into LDS
    #pragma unroll
    for (int j = 0; j < 5; ++j)
        #pragma unroll
        for (int r = 0; r < 4; ++r)
            C[(long)(m0 + wm + q * 4 + r) * 80 + j * 16 + lr] = acc[j][r];
    #pragma unroll
    for (int r = 0; r < 4; ++r)
        sRank[wm + q * 4 + r][lr] = acc[0][r];
    __syncthreads();

    // dt epilogue: thread handles e = tid and e+256 for all 64 rows
    float wta[RNK], wtb[RNK];
    #pragma unroll
    for (int k4 = 0; k4 < 4; ++k4) {
        float4 a4 = *(const float4*)(dtw + tid * RNK + k4 * 4);
        float4 b4 = *(const float4*)(dtw + (tid + 256) * RNK + k4 * 4);
        wta[k4*4+0]=a4.x; wta[k4*4+1]=a4.y; wta[k4*4+2]=a4.z; wta[k4*4+3]=a4.w;
        wtb[k4*4+0]=b4.x; wtb[k4*4+1]=b4.y; wtb[k4*4+2]=b4.z; wtb[k4*4+3]=b4.w;
    }
    const float dtba = dtb[tid], dtbb = dtb[tid + 256];
    for (int rw = 0; rw < 64; ++rw) {
        float ra = dtba, rb = dtbb;
        #pragma unroll
        for (int k4 = 0; k4 < 4; ++k4) {
            float4 rk = *(const float4*)(&sRank[rw][k4 * 4]);
            ra += wta[k4*4+0]*rk.x + wta[k4*4+1]*rk.y + wta[k4*4+2]*rk.z + wta[k4*4+3]*rk.w;
            rb += wtb[k4*4+0]*rk.x + wtb[k4*4+1]*rk.y + wtb[k4*4+2]*rk.z + wtb[k4*4+3]*rk.w;
        }
        dtf[(long)(m0 + rw) * ESZ + tid]       = __float2bfloat16(softplus_f(ra));
        dtf[(long)(m0 + rw) * ESZ + tid + 256] = __float2bfloat16(softplus_f(rb));
    }
}

// ---------------------------------------------------------------------------
// Chunked parallel selective scan [R10-proven direct-exp form]. Lane owns
// channel e, 32 states in regs; B/C in LDS; dt from bf16 dtf; u recomputed
// from bf16 xz. 32 INDEPENDENT exps per t (ILP-friendly; the R11 factorized
// serial-multiply chain blew VGPR to 256 and regressed 4x — do not repeat).
// P/Q bf16. Grid 512. Layout [b][c][n][e].
// ---------------------------------------------------------------------------
__global__ __launch_bounds__(256) void scan_s1(
    const __hip_bfloat16* __restrict__ xz, const float* __restrict__ dbl,
    const __hip_bfloat16* __restrict__ dtf, const float* __restrict__ A_log,
    const float* __restrict__ scw, const float* __restrict__ scb,
    __hip_bfloat16* __restrict__ P, __hip_bfloat16* __restrict__ Q)
{
    const int tid = threadIdx.x;
    const int e  = ((blockIdx.x & 1) << 8) + tid;
    const int bc = blockIdx.x >> 1;
    const int c  = bc & (NCH - 1);
    const int b  = bc >> 6;

    __shared__ float sBC[CHL][64];   // [t][0:32]=B, [32:64]=C
    {
        const int r  = tid >> 4;
        const int cg = (tid & 15) * 4;
        *(float4*)&sBC[r][cg] =
            *(const float4*)(dbl + ((long)b * LSEQ + c * CHL + r) * 80 + 16 + cg);
    }

    float Aen[NST];
    #pragma unroll
    for (int qd = 0; qd < 8; ++qd) {
        float4 a4 = *(const float4*)(A_log + e * NST + qd * 4);
        Aen[qd * 4 + 0] = -__expf(a4.x);
        Aen[qd * 4 + 1] = -__expf(a4.y);
        Aen[qd * 4 + 2] = -__expf(a4.z);
        Aen[qd * 4 + 3] = -__expf(a4.w);
    }
    float cw4[4];
    #pragma unroll
    for (int k = 0; k < 4; ++k) cw4[k] = scw[e * 4 + k];
    const float cbe = scb[e];

    const int l0 = c * CHL;
    const long rowbase = ((long)b * LSEQ) * 1024 + e;
    float xw0, xw1, xw2;
    if (c == 0) { xw0 = xw1 = xw2 = 0.f; }
    else {
        xw0 = __bfloat162float(xz[rowbase + (long)(l0 - 3) * 1024]);
        xw1 = __bfloat162float(xz[rowbase + (long)(l0 - 2) * 1024]);
        xw2 = __bfloat162float(xz[rowbase + (long)(l0 - 1) * 1024]);
    }

    float Pv[NST], Qv[NST];
    #pragma unroll
    for (int n = 0; n < NST; ++n) { Pv[n] = 1.f; Qv[n] = 0.f; }
    __syncthreads();

    for (int t = 0; t < CHL; ++t) {
        const int l = l0 + t;
        const long bl = (long)b * LSEQ + l;
        float xw3 = __bfloat162float(xz[rowbase + (long)l * 1024]);
        float u = silu_f(cbe + cw4[0]*xw0 + cw4[1]*xw1 + cw4[2]*xw2 + cw4[3]*xw3);
        xw0 = xw1; xw1 = xw2; xw2 = xw3;

        float dt = __bfloat162float(dtf[bl * ESZ + e]);
        float xx = dt * u;

        #pragma unroll
        for (int qd = 0; qd < 8; ++qd) {
            float4 b4 = *(const float4*)&sBC[t][qd * 4];
            #pragma unroll
            for (int j = 0; j < 4; ++j) {
                const int n = qd * 4 + j;
                float bn = (j == 0) ? b4.x : (j == 1) ? b4.y : (j == 2) ? b4.z : b4.w;
                float dA = __expf(dt * Aen[n]);
                Pv[n] *= dA;
                Qv[n] = fmaf(dA, Qv[n], xx * bn);
            }
        }
    }
    const long pb = ((long)(b * NCH + c) * NST) * ESZ + e;
    #pragma unroll
    for (int n = 0; n < NST; ++n) {
        P[pb + (long)n * ESZ] = __float2bfloat16(Pv[n]);
        Q[pb + (long)n * ESZ] = __float2bfloat16(Qv[n]);
    }
}

__global__ __launch_bounds__(256) void scan_s2(
    __hip_bfloat16* __restrict__ P, const __hip_bfloat16* __restrict__ Q)
{
    const int tg = blockIdx.x * 256 + threadIdx.x;   // 65536 = B*NST*E
    const int e  = tg & (ESZ - 1);
    const int n  = (tg >> 9) & (NST - 1);
    const int b  = tg >> 14;
    float h = 0.f;
    #pragma unroll 4
    for (int c = 0; c < NCH; ++c) {
        const long idx = ((long)(b * NCH + c) * NST + n) * ESZ + e;
        float Pv = __bfloat162float(P[idx]);
        float Qv = __bfloat162float(Q[idx]);
        P[idx] = __float2bfloat16(h);
        h = fmaf(Pv, h, Qv);
    }
}

__global__ __launch_bounds__(256) void scan_s3(
    const __hip_bfloat16* __restrict__ xz, const float* __restrict__ dbl,
    const __hip_bfloat16* __restrict__ dtf, const float* __restrict__ A_log,
    const float* __restrict__ scw, const float* __restrict__ scb,
    const float* __restrict__ Dp, const __hip_bfloat16* __restrict__ H,
    __hip_bfloat16* __restrict__ yg)
{
    const int tid = threadIdx.x;
    const int e  = ((blockIdx.x & 1) << 8) + tid;
    const int bc = blockIdx.x >> 1;
    const int c  = bc & (NCH - 1);
    const int b  = bc >> 6;

    __shared__ float sBC[CHL][64];
    {
        const int r  = tid >> 4;
        const int cg = (tid & 15) * 4;
        *(float4*)&sBC[r][cg] =
            *(const float4*)(dbl + ((long)b * LSEQ + c * CHL + r) * 80 + 16 + cg);
    }

    float Aen[NST];
    #pragma unroll
    for (int qd = 0; qd < 8; ++qd) {
        float4 a4 = *(const float4*)(A_log + e * NST + qd * 4);
        Aen[qd * 4 + 0] = -__expf(a4.x);
        Aen[qd * 4 + 1] = -__expf(a4.y);
        Aen[qd * 4 + 2] = -__expf(a4.z);
        Aen[qd * 4 + 3] = -__expf(a4.w);
    }
    float cw4[4];
    #pragma unroll
    for (int k = 0; k < 4; ++k) cw4[k] = scw[e * 4 + k];
    const float cbe = scb[e];
    const float dpe = Dp[e];

    float h[NST];
    const long pb = ((long)(b * NCH + c) * NST) * ESZ + e;
    #pragma unroll
    for (int n = 0; n < NST; ++n)
        h[n] = __bfloat162float(H[pb + (long)n * ESZ]);

    const int l0 = c * CHL;
    const long rowbase = ((long)b * LSEQ) * 1024 + e;
    float xw0, xw1, xw2;
    if (c == 0) { xw0 = xw1 = xw2 = 0.f; }
    else {
        xw0 = __bfloat162float(xz[rowbase + (long)(l0 - 3) * 1024]);
        xw1 = __bfloat162float(xz[rowbase + (long)(l0 - 2) * 1024]);
        xw2 = __bfloat162float(xz[rowbase + (long)(l0 - 1) * 1024]);
    }
    __syncthreads();

    for (int t = 0; t < CHL; ++t) {
        const int l = l0 + t;
        const long bl = (long)b * LSEQ + l;
        float xw3 = __bfloat162float(xz[rowbase + (long)l * 1024]);
        float u = silu_f(cbe + cw4[0]*xw0 + cw4[1]*xw1 + cw4[2]*xw2 + cw4[3]*xw3);
        xw0 = xw1; xw1 = xw2; xw2 = xw3;

        float dt = __bfloat162float(dtf[bl * ESZ + e]);
        float xx = dt * u;

        float y = 0.f;
        #pragma unroll
        for (int qd = 0; qd < 8; ++qd) {
            float4 b4 = *(const float4*)&sBC[t][qd * 4];
            float4 c4 = *(const float4*)&sBC[t][32 + qd * 4];
            #pragma unroll
            for (int j = 0; j < 4; ++j) {
                const int n = qd * 4 + j;
                float bn = (j == 0) ? b4.x : (j == 1) ? b4.y : (j == 2) ? b4.z : b4.w;
                float cn = (j == 0) ? c4.x : (j == 1) ? c4.y : (j == 2) ? c4.z : c4.w;
                float dA = __expf(dt * Aen[n]);
                h[n] = fmaf(dA, h[n], xx * bn);
                y = fmaf(h[n], cn, y);
            }
        }
        y += u * dpe;
        float z = __bfloat162float(xz[rowbase + (long)l * 1024 + ESZ]);
        yg[bl * ESZ + e] = __float2bfloat16(y * silu_f(z));
    }
}

// ---------------------------------------------------------------------------
extern "C" void kernel_launch(void* const* d_in, const int* in_sizes, int n_in,
                              void* d_out, int out_size, void* d_ws, size_t ws_size,
                              hipStream_t stream)
{
    const float* x    = (const float*)d_in[0];
    const float* n1g  = (const float*)d_in[1];
    const float* n1b  = (const float*)d_in[2];
    const float* cw   = (const float*)d_in[3];
    const float* cb   = (const float*)d_in[4];
    const float* ipw  = (const float*)d_in[5];
    const float* scw  = (const float*)d_in[6];
    const float* scb  = (const float*)d_in[7];
    const float* xpw  = (const float*)d_in[8];
    const float* dtw  = (const float*)d_in[9];
    const float* dtbi = (const float*)d_in[10];
    const float* alog = (const float*)d_in[11];
    const float* dp   = (const float*)d_in[12];
    const float* opw  = (const float*)d_in[13];
    const float* n2g  = (const float*)d_in[14];
    const float* n2b  = (const float*)d_in[15];
    const float* w1   = (const float*)d_in[16];
    const float* b1   = (const float*)d_in[17];
    const float* w2   = (const float*)d_in[18];
    const float* b2   = (const float*)d_in[19];
    float* out = (float*)d_out;

    // Workspace (float units) — disjoint, ~58 MB.
    float* ws = (float*)d_ws;
    __hip_bfloat16* hmb  = (__hip_bfloat16*)(ws + 0);         //   524,288 f
    __hip_bfloat16* xzb  = (__hip_bfloat16*)(ws + 524288);    // 2,097,152 f (4096x1024 bf16)
    __hip_bfloat16* ub   = (__hip_bfloat16*)(ws + 2621440);   // 1,048,576 f
    float*          dbl  = ws + 3670016;                      //   327,680 f
    __hip_bfloat16* dtf  = (__hip_bfloat16*)(ws + 3997696);   // 1,048,576 f (bf16)
    __hip_bfloat16* P    = (__hip_bfloat16*)(ws + 5046272);   // 2,097,152 f (bf16)
    __hip_bfloat16* Q    = (__hip_bfloat16*)(ws + 7143424);   // 2,097,152 f (bf16)
    __hip_bfloat16* ygb  = (__hip_bfloat16*)(ws + 9240576);   // 1,048,576 f
    float*          hres = ws + 10289152;                     // 1,048,576 f
    __hip_bfloat16* h1b  = (__hip_bfloat16*)(ws + 11337728);  //   524,288 f
    __hip_bfloat16* midb = (__hip_bfloat16*)(ws + 11862016);  // 2,097,152 f
    __hip_bfloat16* wb   = (__hip_bfloat16*)(ws + 13959168);  //   479,232 f
    __hip_bfloat16* ipwb = wb;
    __hip_bfloat16* opwb = wb + 262144;
    __hip_bfloat16* w1b  = wb + 393216;
    __hip_bfloat16* w2b  = wb + 655360;
    __hip_bfloat16* xpwb = wb + 917504;

    // 1. weight converts + fused LN1/conv3/residual
    prep_kernel<<<5032, 256, 0, stream>>>(ipw, opw, w1, w2, xpw, wb,
                                          x, n1g, n1b, cw, cb, hmb);
    // 2. in_proj (MFMA) -> bf16 xz: xz = hm @ ipw^T  [4096,1024,256]
    gemm_mfma<64, 128, EPI_NONE, 1><<<dim3(64, 8), 256, 0, stream>>>(
        hmb, 256, ipwb, 256, xzb, 1024, 256, nullptr, nullptr, 0);
    // 3. causal conv4 + silu -> bf16 ub
    conv4_silu_kernel<<<8192, 256, 0, stream>>>(xzb, scw, scb, ub);
    // 4. x_proj (MFMA) + dt epilogue: dbl + dtf in one kernel
    xproj_mfma_dt<<<64, 256, 0, stream>>>(ub, xpwb, dtw, dtbi, dbl, dtf);
    // 5-7. chunked selective scan (bf16 P/Q) -> bf16 yg
    scan_s1<<<512, 256, 0, stream>>>(xzb, dbl, dtf, alog, scw, scb, P, Q);
    scan_s2<<<256, 256, 0, stream>>>(P, Q);
    scan_s3<<<512, 256, 0, stream>>>(xzb, dbl, dtf, alog, scw, scb, dp, P, ygb);
    // 8. out_proj (MFMA) + residual: hres = yg @ opw^T + x
    gemm_mfma<64, 64, EPI_RES, 0><<<dim3(64, 4), 256, 0, stream>>>(
        ygb, 512, opwb, 512, hres, 256, 512, nullptr, x, 256);
    // 9. LN2 -> bf16
    ln_kernel<<<MROWS, 256, 0, stream>>>(hres, n2g, n2b, h1b);
    // 10. MLP1 (MFMA) + gelu -> bf16 mid
    gemm_mfma<64, 128, EPI_GELU, 1><<<dim3(64, 8), 256, 0, stream>>>(
        h1b, 256, w1b, 256, midb, 1024, 256, b1, nullptr, 0);
    // 11. MLP2 (MFMA) + bias + residual -> out
    gemm_mfma<64, 64, EPI_BIAS_RES, 0><<<dim3(64, 4), 256, 0, stream>>>(
        midb, 1024, w2b, 1024, out, 256, 1024, b2, hres, 256);
}

// Round 14
// 272.443 us; speedup vs baseline: 1.1412x; 1.1412x over previous
//
#include <hip/hip_runtime.h>
#include <hip/hip_bf16.h>
#include <math.h>

// Problem constants
#define BATCH 4
#define LSEQ  1024
#define DIM   256
#define ESZ   512      // E = 2*DIM
#define NST   32       // D_STATE
#define RNK   16       // DT_RANK
#define MROWS 4096     // B*L
#define NCH   64       // scan chunks
#define CHL   16       // chunk length

typedef __attribute__((ext_vector_type(8))) short bf16x8;
typedef __attribute__((ext_vector_type(4))) float f32x4;

__device__ __forceinline__ float silu_f(float v) { return v / (1.f + __expf(-v)); }
__device__ __forceinline__ float softplus_f(float v) {
    return (v > 20.f) ? v : log1pf(__expf(v));
}

// ---------------------------------------------------------------------------
// prep: [blocks 0..935] weight fp32->bf16 conversions
//       [blocks 936..5031] fused LN1 + dwconv3 + residual -> bf16 hm
// ---------------------------------------------------------------------------
__global__ __launch_bounds__(256) void prep_kernel(
    const float* __restrict__ ipw, const float* __restrict__ opw,
    const float* __restrict__ w1,  const float* __restrict__ w2,
    const float* __restrict__ xpw, __hip_bfloat16* __restrict__ dst,
    const float* __restrict__ x, const float* __restrict__ g,
    const float* __restrict__ b, const float* __restrict__ cw,
    const float* __restrict__ cb, __hip_bfloat16* __restrict__ hm)
{
    if (blockIdx.x < 936) {
        int i = blockIdx.x * 256 + threadIdx.x;   // over 239616 float4s
        if (i >= 239616) return;
        const float* s; int off;
        if      (i < 65536)  { s = ipw; off = i; }
        else if (i < 98304)  { s = opw; off = i - 65536; }
        else if (i < 163840) { s = w1;  off = i - 98304; }
        else if (i < 229376) { s = w2;  off = i - 163840; }
        else                 { s = xpw; off = i - 229376; }
        float4 v = ((const float4*)s)[off];
        union { __hip_bfloat16 h[4]; short4 s4; } u;
        u.h[0] = __float2bfloat16(v.x);
        u.h[1] = __float2bfloat16(v.y);
        u.h[2] = __float2bfloat16(v.z);
        u.h[3] = __float2bfloat16(v.w);
        ((short4*)dst)[i] = u.s4;
        return;
    }
    const int row = blockIdx.x - 936;
    const int l   = row & (LSEQ - 1);
    const int d   = threadIdx.x;
    const float gc = g[d], bc = b[d];

    float xc = x[row * DIM + d];
    float xl = (l > 0)        ? x[(row - 1) * DIM + d] : 0.f;
    float xr = (l < LSEQ - 1) ? x[(row + 1) * DIM + d] : 0.f;

    float a[6] = { xc, xc * xc, xl, xl * xl, xr, xr * xr };
    #pragma unroll
    for (int o = 32; o > 0; o >>= 1)
        #pragma unroll
        for (int j = 0; j < 6; ++j) a[j] += __shfl_down(a[j], o, 64);
    __shared__ float red[4][6];
    if ((d & 63) == 0)
        #pragma unroll
        for (int j = 0; j < 6; ++j) red[d >> 6][j] = a[j];
    __syncthreads();
    float t[6];
    #pragma unroll
    for (int j = 0; j < 6; ++j)
        t[j] = red[0][j] + red[1][j] + red[2][j] + red[3][j];

    auto ln = [&](float v, float s, float s2) {
        float m  = s * (1.f / DIM);
        float vr = s2 * (1.f / DIM) - m * m;
        return (v - m) * rsqrtf(vr + 1e-5f) * gc + bc;
    };
    float ln_c = ln(xc, t[0], t[1]);
    float acc  = cw[d * 3 + 1] * ln_c + cb[d] + ln_c;
    if (l > 0)        acc += cw[d * 3 + 0] * ln(xl, t[2], t[3]);
    if (l < LSEQ - 1) acc += cw[d * 3 + 2] * ln(xr, t[4], t[5]);
    hm[row * DIM + d] = __float2bfloat16(acc);
}

// ---------------------------------------------------------------------------
// Plain LayerNorm (LN2) -> bf16
// ---------------------------------------------------------------------------
__global__ __launch_bounds__(256) void ln_kernel(
    const float* __restrict__ x, const float* __restrict__ g,
    const float* __restrict__ b, __hip_bfloat16* __restrict__ y)
{
    const int row = blockIdx.x;
    const int tid = threadIdx.x;
    float v = x[row * DIM + tid];
    float s = v, s2 = v * v;
    #pragma unroll
    for (int o = 32; o > 0; o >>= 1) {
        s  += __shfl_down(s,  o, 64);
        s2 += __shfl_down(s2, o, 64);
    }
    __shared__ float ls[4], ls2[4];
    if ((tid & 63) == 0) { ls[tid >> 6] = s; ls2[tid >> 6] = s2; }
    __syncthreads();
    float ts  = ls[0]  + ls[1]  + ls[2]  + ls[3];
    float ts2 = ls2[0] + ls2[1] + ls2[2] + ls2[3];
    float mean = ts * (1.f / DIM);
    float var  = ts2 * (1.f / DIM) - mean * mean;
    float inv  = rsqrtf(var + 1e-5f);
    y[row * DIM + tid] =
        __float2bfloat16((v - mean) * inv * g[tid] + b[tid]);
}

// ---------------------------------------------------------------------------
// causal dwconv4 + SiLU -> bf16 ub (for x_proj). Reads bf16 xz.
// ---------------------------------------------------------------------------
__global__ __launch_bounds__(256) void conv4_silu_kernel(
    const __hip_bfloat16* __restrict__ xz, const float* __restrict__ w,
    const float* __restrict__ cb, __hip_bfloat16* __restrict__ ub)
{
    const int i  = blockIdx.x * 256 + threadIdx.x;   // over 4096*512
    const int e  = i & (ESZ - 1);
    const int bl = i >> 9;
    const int l  = bl & (LSEQ - 1);
    float acc = cb[e];
    #pragma unroll
    for (int k = 0; k < 4; ++k) {
        int ls = l + k - 3;
        if (ls >= 0)
            acc += w[e * 4 + k] * __bfloat162float(xz[(long)(bl + k - 3) * 1024 + e]);
    }
    ub[(long)bl * ESZ + e] = __float2bfloat16(silu_f(acc));
}

// ---------------------------------------------------------------------------
// dt precompute -> bf16: dtf[row,e] = softplus(dtb[e] + dbl[row,:16].dtw[e,:])
// Kept SEPARATE: R13 proved fusing this into xproj's 64-block epilogue costs
// 59 µs (tail runs at 64-block parallelism) vs ~5 µs standalone at 4096 blocks.
// ---------------------------------------------------------------------------
__global__ __launch_bounds__(256) void dt_kernel(
    const float* __restrict__ dbl, const float* __restrict__ dtw,
    const float* __restrict__ dtb, __hip_bfloat16* __restrict__ dtf)
{
    const int row = blockIdx.x;
    __shared__ float dr[RNK];
    if (threadIdx.x < RNK) dr[threadIdx.x] = dbl[(long)row * 80 + threadIdx.x];
    __syncthreads();
    #pragma unroll
    for (int hh = 0; hh < 2; ++hh) {
        const int e = threadIdx.x + hh * 256;
        float raw = dtb[e];
        #pragma unroll
        for (int qd = 0; qd < 4; ++qd) {
            float4 w4 = *(const float4*)(dtw + e * RNK + qd * 4);
            raw += w4.x * dr[qd * 4 + 0] + w4.y * dr[qd * 4 + 1]
                 + w4.z * dr[qd * 4 + 2] + w4.w * dr[qd * 4 + 3];
        }
        dtf[(long)row * ESZ + e] = __float2bfloat16(softplus_f(raw));
    }
}

// ---------------------------------------------------------------------------
// Epilogue ids
// ---------------------------------------------------------------------------
#define EPI_NONE      0
#define EPI_GELU      2
#define EPI_RES       3
#define EPI_BIAS_RES  4

// ---------------------------------------------------------------------------
// bf16 MFMA GEMM with reg prefetch. C = A @ W^T (+ epilogue). BM=64.
// ---------------------------------------------------------------------------
template <int BM, int BN, int EPI, int OUT_BF16>
__global__ __launch_bounds__(256) void gemm_mfma(
    const __hip_bfloat16* __restrict__ A, int lda,
    const __hip_bfloat16* __restrict__ W, int ldw,
    void* __restrict__ Cout, int ldc, int K,
    const float* __restrict__ bias,
    const float* __restrict__ res, int ldres)
{
    constexpr int BK = 64;
    constexpr int LS = BK + 8;
    constexpr int WAVES_N = 4;
    constexpr int WTN = BN / WAVES_N;
    constexpr int AMF = 4;
    constexpr int BNF = WTN / 16;
    constexpr int AR = BM / 32;
    constexpr int BR = BN / 32;

    __shared__ __hip_bfloat16 As[BM * LS];
    __shared__ __hip_bfloat16 Ws[BN * LS];

    const int tid  = threadIdx.x;
    const int lane = tid & 63;
    const int wave = tid >> 6;
    const int wn   = wave * WTN;
    const int m0   = blockIdx.x * BM;
    const int n0   = blockIdx.y * BN;
    const int srow = tid >> 3;
    const int scol = (tid & 7) * 8;
    const int q    = lane >> 4;
    const int lr   = lane & 15;

    f32x4 acc[AMF][BNF];
    #pragma unroll
    for (int i = 0; i < AMF; ++i)
        #pragma unroll
        for (int j = 0; j < BNF; ++j)
            acc[i][j] = (f32x4){0.f, 0.f, 0.f, 0.f};

    const __hip_bfloat16* Ab = A + (long)m0 * lda;
    const __hip_bfloat16* Wb = W + (long)n0 * ldw;

    float4 ar[AR], wr[BR];
    #pragma unroll
    for (int r = 0; r < AR; ++r)
        ar[r] = *(const float4*)(Ab + (long)(r * 32 + srow) * lda + scol);
    #pragma unroll
    for (int r = 0; r < BR; ++r)
        wr[r] = *(const float4*)(Wb + (long)(r * 32 + srow) * ldw + scol);

    for (int k0 = 0; k0 < K; k0 += BK) {
        __syncthreads();
        #pragma unroll
        for (int r = 0; r < AR; ++r)
            *(float4*)(&As[(r * 32 + srow) * LS + scol]) = ar[r];
        #pragma unroll
        for (int r = 0; r < BR; ++r)
            *(float4*)(&Ws[(r * 32 + srow) * LS + scol]) = wr[r];
        __syncthreads();
        if (k0 + BK < K) {
            #pragma unroll
            for (int r = 0; r < AR; ++r)
                ar[r] = *(const float4*)(Ab + (long)(r * 32 + srow) * lda + k0 + BK + scol);
            #pragma unroll
            for (int r = 0; r < BR; ++r)
                wr[r] = *(const float4*)(Wb + (long)(r * 32 + srow) * ldw + k0 + BK + scol);
        }
        #pragma unroll
        for (int ks = 0; ks < 2; ++ks) {
            bf16x8 af[AMF], bfr[BNF];
            #pragma unroll
            for (int i = 0; i < AMF; ++i)
                af[i] = *(const bf16x8*)(&As[(i * 16 + lr) * LS + ks * 32 + q * 8]);
            #pragma unroll
            for (int j = 0; j < BNF; ++j)
                bfr[j] = *(const bf16x8*)(&Ws[(wn + j * 16 + lr) * LS + ks * 32 + q * 8]);
            #pragma unroll
            for (int i = 0; i < AMF; ++i)
                #pragma unroll
                for (int j = 0; j < BNF; ++j)
                    acc[i][j] = __builtin_amdgcn_mfma_f32_16x16x32_bf16(
                        af[i], bfr[j], acc[i][j], 0, 0, 0);
        }
    }

    #pragma unroll
    for (int i = 0; i < AMF; ++i) {
        #pragma unroll
        for (int j = 0; j < BNF; ++j) {
            const int col  = n0 + wn + j * 16 + lr;
            const int rowb = m0 + i * 16 + q * 4;
            #pragma unroll
            for (int r = 0; r < 4; ++r) {
                const int row = rowb + r;
                float v = acc[i][j][r];
                if (EPI == EPI_GELU) {
                    v += bias[col];
                    v = 0.5f * v * (1.f + erff(v * 0.70710678118654752f));
                } else if (EPI == EPI_RES) {
                    v += res[(long)row * ldres + col];
                } else if (EPI == EPI_BIAS_RES) {
                    v += bias[col] + res[(long)row * ldres + col];
                }
                if (OUT_BF16)
                    ((__hip_bfloat16*)Cout)[(long)row * ldc + col] = __float2bfloat16(v);
                else
                    ((float*)Cout)[(long)row * ldc + col] = v;
            }
        }
    }
}

// ---------------------------------------------------------------------------
// x_proj MFMA: dbl[4096,80] = ub[4096,512] @ xpwb[80,512]^T, reg prefetch.
// ---------------------------------------------------------------------------
__global__ __launch_bounds__(256) void xproj_mfma(
    const __hip_bfloat16* __restrict__ A,
    const __hip_bfloat16* __restrict__ W,
    float* __restrict__ C)
{
    constexpr int LS = 72;
    __shared__ __hip_bfloat16 As[64 * LS];
    __shared__ __hip_bfloat16 Ws[80 * LS];
    const int tid  = threadIdx.x;
    const int lane = tid & 63;
    const int wave = tid >> 6;
    const int wm   = wave * 16;
    const int m0   = blockIdx.x * 64;
    const int srow = tid >> 3;
    const int scol = (tid & 7) * 8;
    const int q    = lane >> 4;
    const int lr   = lane & 15;

    f32x4 acc[5];
    #pragma unroll
    for (int j = 0; j < 5; ++j) acc[j] = (f32x4){0.f, 0.f, 0.f, 0.f};

    float4 ar[2], wr[3];
    #pragma unroll
    for (int r = 0; r < 2; ++r)
        ar[r] = *(const float4*)(A + (long)(m0 + r * 32 + srow) * 512 + scol);
    #pragma unroll
    for (int r = 0; r < 3; ++r) {
        int row = r * 32 + srow;
        wr[r] = (row < 80) ? *(const float4*)(W + (long)row * 512 + scol)
                           : make_float4(0.f, 0.f, 0.f, 0.f);
    }

    for (int k0 = 0; k0 < 512; k0 += 64) {
        __syncthreads();
        #pragma unroll
        for (int r = 0; r < 2; ++r)
            *(float4*)(&As[(r * 32 + srow) * LS + scol]) = ar[r];
        #pragma unroll
        for (int r = 0; r < 3; ++r) {
            int row = r * 32 + srow;
            if (row < 80) *(float4*)(&Ws[row * LS + scol]) = wr[r];
        }
        __syncthreads();
        if (k0 + 64 < 512) {
            #pragma unroll
            for (int r = 0; r < 2; ++r)
                ar[r] = *(const float4*)(A + (long)(m0 + r * 32 + srow) * 512 + k0 + 64 + scol);
            #pragma unroll
            for (int r = 0; r < 3; ++r) {
                int row = r * 32 + srow;
                if (row < 80)
                    wr[r] = *(const float4*)(W + (long)row * 512 + k0 + 64 + scol);
            }
        }
        #pragma unroll
        for (int ks = 0; ks < 2; ++ks) {
            bf16x8 af = *(const bf16x8*)(&As[(wm + lr) * LS + ks * 32 + q * 8]);
            #pragma unroll
            for (int j = 0; j < 5; ++j) {
                bf16x8 bf = *(const bf16x8*)(&Ws[(j * 16 + lr) * LS + ks * 32 + q * 8]);
                acc[j] = __builtin_amdgcn_mfma_f32_16x16x32_bf16(af, bf, acc[j], 0, 0, 0);
            }
        }
    }
    #pragma unroll
    for (int j = 0; j < 5; ++j)
        #pragma unroll
        for (int r = 0; r < 4; ++r)
            C[(long)(m0 + wm + q * 4 + r) * 80 + j * 16 + lr] = acc[j][r];
}

// ---------------------------------------------------------------------------
// Chunked parallel selective scan [R10-proven direct-exp form]. Lane owns
// channel e, 32 states in regs; B/C in LDS; dt from bf16 dtf; u recomputed
// from bf16 xz. 32 INDEPENDENT exps per t (ILP-friendly; the R11 factorized
// serial-multiply chain blew VGPR to 256 and regressed 4x — do not repeat).
// P/Q bf16. Grid 512. Layout [b][c][n][e].
// ---------------------------------------------------------------------------
__global__ __launch_bounds__(256) void scan_s1(
    const __hip_bfloat16* __restrict__ xz, const float* __restrict__ dbl,
    const __hip_bfloat16* __restrict__ dtf, const float* __restrict__ A_log,
    const float* __restrict__ scw, const float* __restrict__ scb,
    __hip_bfloat16* __restrict__ P, __hip_bfloat16* __restrict__ Q)
{
    const int tid = threadIdx.x;
    const int e  = ((blockIdx.x & 1) << 8) + tid;
    const int bc = blockIdx.x >> 1;
    const int c  = bc & (NCH - 1);
    const int b  = bc >> 6;

    __shared__ float sBC[CHL][64];   // [t][0:32]=B, [32:64]=C
    {
        const int r  = tid >> 4;
        const int cg = (tid & 15) * 4;
        *(float4*)&sBC[r][cg] =
            *(const float4*)(dbl + ((long)b * LSEQ + c * CHL + r) * 80 + 16 + cg);
    }

    float Aen[NST];
    #pragma unroll
    for (int qd = 0; qd < 8; ++qd) {
        float4 a4 = *(const float4*)(A_log + e * NST + qd * 4);
        Aen[qd * 4 + 0] = -__expf(a4.x);
        Aen[qd * 4 + 1] = -__expf(a4.y);
        Aen[qd * 4 + 2] = -__expf(a4.z);
        Aen[qd * 4 + 3] = -__expf(a4.w);
    }
    float cw4[4];
    #pragma unroll
    for (int k = 0; k < 4; ++k) cw4[k] = scw[e * 4 + k];
    const float cbe = scb[e];

    const int l0 = c * CHL;
    const long rowbase = ((long)b * LSEQ) * 1024 + e;
    float xw0, xw1, xw2;
    if (c == 0) { xw0 = xw1 = xw2 = 0.f; }
    else {
        xw0 = __bfloat162float(xz[rowbase + (long)(l0 - 3) * 1024]);
        xw1 = __bfloat162float(xz[rowbase + (long)(l0 - 2) * 1024]);
        xw2 = __bfloat162float(xz[rowbase + (long)(l0 - 1) * 1024]);
    }

    float Pv[NST], Qv[NST];
    #pragma unroll
    for (int n = 0; n < NST; ++n) { Pv[n] = 1.f; Qv[n] = 0.f; }
    __syncthreads();

    for (int t = 0; t < CHL; ++t) {
        const int l = l0 + t;
        const long bl = (long)b * LSEQ + l;
        float xw3 = __bfloat162float(xz[rowbase + (long)l * 1024]);
        float u = silu_f(cbe + cw4[0]*xw0 + cw4[1]*xw1 + cw4[2]*xw2 + cw4[3]*xw3);
        xw0 = xw1; xw1 = xw2; xw2 = xw3;

        float dt = __bfloat162float(dtf[bl * ESZ + e]);
        float xx = dt * u;

        #pragma unroll
        for (int qd = 0; qd < 8; ++qd) {
            float4 b4 = *(const float4*)&sBC[t][qd * 4];
            #pragma unroll
            for (int j = 0; j < 4; ++j) {
                const int n = qd * 4 + j;
                float bn = (j == 0) ? b4.x : (j == 1) ? b4.y : (j == 2) ? b4.z : b4.w;
                float dA = __expf(dt * Aen[n]);
                Pv[n] *= dA;
                Qv[n] = fmaf(dA, Qv[n], xx * bn);
            }
        }
    }
    const long pb = ((long)(b * NCH + c) * NST) * ESZ + e;
    #pragma unroll
    for (int n = 0; n < NST; ++n) {
        P[pb + (long)n * ESZ] = __float2bfloat16(Pv[n]);
        Q[pb + (long)n * ESZ] = __float2bfloat16(Qv[n]);
    }
}

__global__ __launch_bounds__(256) void scan_s2(
    __hip_bfloat16* __restrict__ P, const __hip_bfloat16* __restrict__ Q)
{
    const int tg = blockIdx.x * 256 + threadIdx.x;   // 65536 = B*NST*E
    const int e  = tg & (ESZ - 1);
    const int n  = (tg >> 9) & (NST - 1);
    const int b  = tg >> 14;
    float h = 0.f;
    #pragma unroll 4
    for (int c = 0; c < NCH; ++c) {
        const long idx = ((long)(b * NCH + c) * NST + n) * ESZ + e;
        float Pv = __bfloat162float(P[idx]);
        float Qv = __bfloat162float(Q[idx]);
        P[idx] = __float2bfloat16(h);
        h = fmaf(Pv, h, Qv);
    }
}

__global__ __launch_bounds__(256) void scan_s3(
    const __hip_bfloat16* __restrict__ xz, const float* __restrict__ dbl,
    const __hip_bfloat16* __restrict__ dtf, const float* __restrict__ A_log,
    const float* __restrict__ scw, const float* __restrict__ scb,
    const float* __restrict__ Dp, const __hip_bfloat16* __restrict__ H,
    __hip_bfloat16* __restrict__ yg)
{
    const int tid = threadIdx.x;
    const int e  = ((blockIdx.x & 1) << 8) + tid;
    const int bc = blockIdx.x >> 1;
    const int c  = bc & (NCH - 1);
    const int b  = bc >> 6;

    __shared__ float sBC[CHL][64];
    {
        const int r  = tid >> 4;
        const int cg = (tid & 15) * 4;
        *(float4*)&sBC[r][cg] =
            *(const float4*)(dbl + ((long)b * LSEQ + c * CHL + r) * 80 + 16 + cg);
    }

    float Aen[NST];
    #pragma unroll
    for (int qd = 0; qd < 8; ++qd) {
        float4 a4 = *(const float4*)(A_log + e * NST + qd * 4);
        Aen[qd * 4 + 0] = -__expf(a4.x);
        Aen[qd * 4 + 1] = -__expf(a4.y);
        Aen[qd * 4 + 2] = -__expf(a4.z);
        Aen[qd * 4 + 3] = -__expf(a4.w);
    }
    float cw4[4];
    #pragma unroll
    for (int k = 0; k < 4; ++k) cw4[k] = scw[e * 4 + k];
    const float cbe = scb[e];
    const float dpe = Dp[e];

    float h[NST];
    const long pb = ((long)(b * NCH + c) * NST) * ESZ + e;
    #pragma unroll
    for (int n = 0; n < NST; ++n)
        h[n] = __bfloat162float(H[pb + (long)n * ESZ]);

    const int l0 = c * CHL;
    const long rowbase = ((long)b * LSEQ) * 1024 + e;
    float xw0, xw1, xw2;
    if (c == 0) { xw0 = xw1 = xw2 = 0.f; }
    else {
        xw0 = __bfloat162float(xz[rowbase + (long)(l0 - 3) * 1024]);
        xw1 = __bfloat162float(xz[rowbase + (long)(l0 - 2) * 1024]);
        xw2 = __bfloat162float(xz[rowbase + (long)(l0 - 1) * 1024]);
    }
    __syncthreads();

    for (int t = 0; t < CHL; ++t) {
        const int l = l0 + t;
        const long bl = (long)b * LSEQ + l;
        float xw3 = __bfloat162float(xz[rowbase + (long)l * 1024]);
        float u = silu_f(cbe + cw4[0]*xw0 + cw4[1]*xw1 + cw4[2]*xw2 + cw4[3]*xw3);
        xw0 = xw1; xw1 = xw2; xw2 = xw3;

        float dt = __bfloat162float(dtf[bl * ESZ + e]);
        float xx = dt * u;

        float y = 0.f;
        #pragma unroll
        for (int qd = 0; qd < 8; ++qd) {
            float4 b4 = *(const float4*)&sBC[t][qd * 4];
            float4 c4 = *(const float4*)&sBC[t][32 + qd * 4];
            #pragma unroll
            for (int j = 0; j < 4; ++j) {
                const int n = qd * 4 + j;
                float bn = (j == 0) ? b4.x : (j == 1) ? b4.y : (j == 2) ? b4.z : b4.w;
                float cn = (j == 0) ? c4.x : (j == 1) ? c4.y : (j == 2) ? c4.z : c4.w;
                float dA = __expf(dt * Aen[n]);
                h[n] = fmaf(dA, h[n], xx * bn);
                y = fmaf(h[n], cn, y);
            }
        }
        y += u * dpe;
        float z = __bfloat162float(xz[rowbase + (long)l * 1024 + ESZ]);
        yg[bl * ESZ + e] = __float2bfloat16(y * silu_f(z));
    }
}

// ---------------------------------------------------------------------------
extern "C" void kernel_launch(void* const* d_in, const int* in_sizes, int n_in,
                              void* d_out, int out_size, void* d_ws, size_t ws_size,
                              hipStream_t stream)
{
    const float* x    = (const float*)d_in[0];
    const float* n1g  = (const float*)d_in[1];
    const float* n1b  = (const float*)d_in[2];
    const float* cw   = (const float*)d_in[3];
    const float* cb   = (const float*)d_in[4];
    const float* ipw  = (const float*)d_in[5];
    const float* scw  = (const float*)d_in[6];
    const float* scb  = (const float*)d_in[7];
    const float* xpw  = (const float*)d_in[8];
    const float* dtw  = (const float*)d_in[9];
    const float* dtbi = (const float*)d_in[10];
    const float* alog = (const float*)d_in[11];
    const float* dp   = (const float*)d_in[12];
    const float* opw  = (const float*)d_in[13];
    const float* n2g  = (const float*)d_in[14];
    const float* n2b  = (const float*)d_in[15];
    const float* w1   = (const float*)d_in[16];
    const float* b1   = (const float*)d_in[17];
    const float* w2   = (const float*)d_in[18];
    const float* b2   = (const float*)d_in[19];
    float* out = (float*)d_out;

    // Workspace (float units) — disjoint, ~58 MB.
    float* ws = (float*)d_ws;
    __hip_bfloat16* hmb  = (__hip_bfloat16*)(ws + 0);         //   524,288 f
    __hip_bfloat16* xzb  = (__hip_bfloat16*)(ws + 524288);    // 2,097,152 f (4096x1024 bf16)
    __hip_bfloat16* ub   = (__hip_bfloat16*)(ws + 2621440);   // 1,048,576 f
    float*          dbl  = ws + 3670016;                      //   327,680 f
    __hip_bfloat16* dtf  = (__hip_bfloat16*)(ws + 3997696);   // 1,048,576 f (bf16)
    __hip_bfloat16* P    = (__hip_bfloat16*)(ws + 5046272);   // 2,097,152 f (bf16)
    __hip_bfloat16* Q    = (__hip_bfloat16*)(ws + 7143424);   // 2,097,152 f (bf16)
    __hip_bfloat16* ygb  = (__hip_bfloat16*)(ws + 9240576);   // 1,048,576 f
    float*          hres = ws + 10289152;                     // 1,048,576 f
    __hip_bfloat16* h1b  = (__hip_bfloat16*)(ws + 11337728);  //   524,288 f
    __hip_bfloat16* midb = (__hip_bfloat16*)(ws + 11862016);  // 2,097,152 f
    __hip_bfloat16* wb   = (__hip_bfloat16*)(ws + 13959168);  //   479,232 f
    __hip_bfloat16* ipwb = wb;
    __hip_bfloat16* opwb = wb + 262144;
    __hip_bfloat16* w1b  = wb + 393216;
    __hip_bfloat16* w2b  = wb + 655360;
    __hip_bfloat16* xpwb = wb + 917504;

    // 1. weight converts + fused LN1/conv3/residual
    prep_kernel<<<5032, 256, 0, stream>>>(ipw, opw, w1, w2, xpw, wb,
                                          x, n1g, n1b, cw, cb, hmb);
    // 2. in_proj (MFMA) -> bf16 xz: xz = hm @ ipw^T  [4096,1024,256]
    gemm_mfma<64, 128, EPI_NONE, 1><<<dim3(64, 8), 256, 0, stream>>>(
        hmb, 256, ipwb, 256, xzb, 1024, 256, nullptr, nullptr, 0);
    // 3. causal conv4 + silu -> bf16 ub
    conv4_silu_kernel<<<8192, 256, 0, stream>>>(xzb, scw, scb, ub);
    // 4. x_proj (MFMA): dbl = ub @ xpw^T  [4096,80,512]
    xproj_mfma<<<64, 256, 0, stream>>>(ub, xpwb, dbl);
    // 5. dt precompute -> bf16
    dt_kernel<<<MROWS, 256, 0, stream>>>(dbl, dtw, dtbi, dtf);
    // 6-8. chunked selective scan (bf16 P/Q) -> bf16 yg
    scan_s1<<<512, 256, 0, stream>>>(xzb, dbl, dtf, alog, scw, scb, P, Q);
    scan_s2<<<256, 256, 0, stream>>>(P, Q);
    scan_s3<<<512, 256, 0, stream>>>(xzb, dbl, dtf, alog, scw, scb, dp, P, ygb);
    // 9. out_proj (MFMA) + residual: hres = yg @ opw^T + x
    gemm_mfma<64, 64, EPI_RES, 0><<<dim3(64, 4), 256, 0, stream>>>(
        ygb, 512, opwb, 512, hres, 256, 512, nullptr, x, 256);
    // 10. LN2 -> bf16
    ln_kernel<<<MROWS, 256, 0, stream>>>(hres, n2g, n2b, h1b);
    // 11. MLP1 (MFMA) + gelu -> bf16 mid
    gemm_mfma<64, 128, EPI_GELU, 1><<<dim3(64, 8), 256, 0, stream>>>(
        h1b, 256, w1b, 256, midb, 1024, 256, b1, nullptr, 0);
    // 12. MLP2 (MFMA) + bias + residual -> out
    gemm_mfma<64, 64, EPI_BIAS_RES, 0><<<dim3(64, 4), 256, 0, stream>>>(
        midb, 1024, w2b, 1024, out, 256, 1024, b2, hres, 256);
}